// Round 6
// baseline (975.659 us; speedup 1.0000x reference)
//
#include <hip/hip_runtime.h>
#include <hip/hip_bf16.h>

#define NV 778
#define NJ 16
#define NBETA 10
#define NP 135
#define NTHETA 15
#define SD_COLS 2334   // NV*3
#define NBAT 16        // batches per block in k_vert

__device__ __constant__ int c_par[16] = {-1,0,1,2,0,4,5,0,7,8,0,10,11,0,13,14};

// ---------------- Kernel 1: SJ[k][j][c] (10x16x3) and Jt[j][c] (16x3) ----------------
__global__ void k_prejoint(const float* __restrict__ sd, const float* __restrict__ vt,
                           const float* __restrict__ Jr,
                           float* __restrict__ SJ, float* __restrict__ Jt)
{
    int o = blockIdx.x * blockDim.x + threadIdx.x;
    if (o < 480) {
        int k = o / 48, rem = o % 48, j = rem / 3, c = rem % 3;
        float acc = 0.f;
        for (int v = 0; v < NV; ++v) acc += sd[k * SD_COLS + v * 3 + c] * Jr[v * NJ + j];
        SJ[o] = acc;
    } else if (o < 528) {
        int idx = o - 480, j = idx / 3, c = idx % 3;
        float acc = 0.f;
        for (int v = 0; v < NV; ++v) acc += vt[v * 3 + c] * Jr[v * NJ + j];
        Jt[idx] = acc;
    }
}

// ---------------- Kernel 2: per-batch pose -> Rs -> chain -> A, pose_feature --------
__global__ __launch_bounds__(64) void k_batch(
    const float* __restrict__ beta, const float* __restrict__ theta,
    const float* __restrict__ hm, const float* __restrict__ hc,
    const float* __restrict__ SJ, const float* __restrict__ Jt,
    float* __restrict__ Aws, float* __restrict__ pfws)
{
    const int b = blockIdx.x;
    const int t = threadIdx.x;
    __shared__ float th48[48];
    __shared__ float Rsh[16][9];
    __shared__ float JL[16][3];

    // step 1: full pose = g_rot ++ (pose12 @ hc[:12] + hm)
    if (t < 45) {
        float acc = hm[t];
        #pragma unroll
        for (int k = 0; k < 12; ++k) acc += theta[b * NTHETA + 3 + k] * hc[k * 45 + t];
        th48[3 + t] = acc;
    }
    if (t >= 45 && t < 48) th48[t - 45] = theta[b * NTHETA + (t - 45)];
    __syncthreads();

    // step 2: t<16 Rodrigues; t in [16,64) -> J = Jt + beta @ SJ
    if (t < 16) {
        float tx = th48[3 * t], ty = th48[3 * t + 1], tz = th48[3 * t + 2];
        float px = tx + 1e-8f, py = ty + 1e-8f, pz = tz + 1e-8f;
        float ang = sqrtf(px * px + py * py + pz * pz);
        float nx = tx / ang, ny = ty / ang, nz = tz / ang;
        float half = 0.5f * ang;
        float w = cosf(half), s = sinf(half);
        float qx = s * nx, qy = s * ny, qz = s * nz;
        float qn = sqrtf(w * w + qx * qx + qy * qy + qz * qz);
        w /= qn; qx /= qn; qy /= qn; qz /= qn;
        float w2 = w * w, x2 = qx * qx, y2 = qy * qy, z2 = qz * qz;
        float wx = w * qx, wy = w * qy, wz = w * qz;
        float xy = qx * qy, xz = qx * qz, yz = qy * qz;
        float* R = Rsh[t];
        R[0] = w2 + x2 - y2 - z2; R[1] = 2.f * xy - 2.f * wz; R[2] = 2.f * wy + 2.f * xz;
        R[3] = 2.f * wz + 2.f * xy; R[4] = w2 - x2 + y2 - z2; R[5] = 2.f * yz - 2.f * wx;
        R[6] = 2.f * xz - 2.f * wy; R[7] = 2.f * wx + 2.f * yz; R[8] = w2 - x2 - y2 + z2;
    } else {
        int idx = t - 16;           // 0..47
        int j = idx / 3, c = idx % 3;
        float acc = Jt[idx];
        #pragma unroll
        for (int k = 0; k < NBETA; ++k) acc += beta[b * NBETA + k] * SJ[k * 48 + idx];
        JL[j][c] = acc;
    }
    __syncthreads();

    // step 3: t<16 kinematic chain -> A; others pose_feature
    if (t < 16) {
        int path[4]; int d = 0; int i = t;
        while (i >= 0) { path[d++] = i; i = c_par[i]; }
        float GR[9], Gt3[3];
        #pragma unroll
        for (int e = 0; e < 9; ++e) GR[e] = Rsh[0][e];
        Gt3[0] = JL[0][0]; Gt3[1] = JL[0][1]; Gt3[2] = JL[0][2];
        for (int s2 = d - 2; s2 >= 0; --s2) {
            int i2 = path[s2];
            int pa = c_par[i2];
            float ti0 = JL[i2][0] - JL[pa][0];
            float ti1 = JL[i2][1] - JL[pa][1];
            float ti2 = JL[i2][2] - JL[pa][2];
            float NR[9], Nt[3];
            #pragma unroll
            for (int r = 0; r < 3; ++r) {
                #pragma unroll
                for (int c = 0; c < 3; ++c) {
                    NR[r * 3 + c] = GR[r * 3 + 0] * Rsh[i2][0 * 3 + c]
                                  + GR[r * 3 + 1] * Rsh[i2][1 * 3 + c]
                                  + GR[r * 3 + 2] * Rsh[i2][2 * 3 + c];
                }
                Nt[r] = GR[r * 3 + 0] * ti0 + GR[r * 3 + 1] * ti1 + GR[r * 3 + 2] * ti2 + Gt3[r];
            }
            #pragma unroll
            for (int e = 0; e < 9; ++e) GR[e] = NR[e];
            Gt3[0] = Nt[0]; Gt3[1] = Nt[1]; Gt3[2] = Nt[2];
        }
        float jx = JL[t][0], jy = JL[t][1], jz = JL[t][2];
        float* A = Aws + (size_t)b * 192 + t * 12;
        #pragma unroll
        for (int r = 0; r < 3; ++r) {
            A[r * 4 + 0] = GR[r * 3 + 0];
            A[r * 4 + 1] = GR[r * 3 + 1];
            A[r * 4 + 2] = GR[r * 3 + 2];
            A[r * 4 + 3] = Gt3[r] - (GR[r * 3 + 0] * jx + GR[r * 3 + 1] * jy + GR[r * 3 + 2] * jz);
        }
    } else {
        int idx = t - 16;           // 0..47
        #pragma unroll
        for (int it = 0; it < 3; ++it) {
            int p = idx + it * 48;
            if (p < NP) {
                int j = 1 + p / 9, e = p % 9;
                float dlt = (e == 0 || e == 4 || e == 8) ? 1.f : 0.f;
                pfws[(size_t)b * NP + p] = Rsh[j][e] - dlt;
            }
        }
    }
}

// ---------------- Kernel 3: vertices + skinning + joint regression ------------------
__global__ __launch_bounds__(256) void k_vert(
    const float* __restrict__ beta, const float* __restrict__ sd, const float* __restrict__ pd,
    const float* __restrict__ vt, const float* __restrict__ Jr, const float* __restrict__ W,
    const float* __restrict__ Aws, const float* __restrict__ pfws,
    float* __restrict__ out)
{
    __shared__ float vertLDS[256 * 50];   // stride 50 breaks the stride-48 bank aliasing
    const int tid = threadIdx.x;
    const int bbase = blockIdx.x * NBAT;
    const int rb = tid & 15;    // batch for reduction phase
    const int rj = tid >> 4;    // output joint for reduction phase
    float jacc0 = 0.f, jacc1 = 0.f, jacc2 = 0.f;

    for (int tile = 0; tile < 4; ++tile) {
        const int v = tile * 256 + tid;
        const bool valid = v < NV;
        float vx[NBAT], vy[NBAT], vz[NBAT];
        float wrow[NJ];

        if (valid) {
            float sdc0[NBETA], sdc1[NBETA], sdc2[NBETA];
            #pragma unroll
            for (int k = 0; k < NBETA; ++k) {
                sdc0[k] = sd[k * SD_COLS + v * 3 + 0];
                sdc1[k] = sd[k * SD_COLS + v * 3 + 1];
                sdc2[k] = sd[k * SD_COLS + v * 3 + 2];
            }
            float vt0 = vt[v * 3 + 0], vt1 = vt[v * 3 + 1], vt2 = vt[v * 3 + 2];
            #pragma unroll
            for (int b = 0; b < NBAT; ++b) {
                float ax = vt0, ay = vt1, az = vt2;
                #pragma unroll
                for (int k = 0; k < NBETA; ++k) {
                    float be = beta[(size_t)(bbase + b) * NBETA + k];   // uniform -> s_load
                    ax += be * sdc0[k]; ay += be * sdc1[k]; az += be * sdc2[k];
                }
                vx[b] = ax; vy[b] = ay; vz[b] = az;
            }
            // pose-blend: 135-dim dot per (b, component)
            for (int p = 0; p < NP; ++p) {
                float p0 = pd[p * SD_COLS + v * 3 + 0];
                float p1 = pd[p * SD_COLS + v * 3 + 1];
                float p2 = pd[p * SD_COLS + v * 3 + 2];
                #pragma unroll
                for (int b = 0; b < NBAT; ++b) {
                    float f = pfws[(size_t)(bbase + b) * NP + p];       // uniform -> s_load
                    vx[b] += f * p0; vy[b] += f * p1; vz[b] += f * p2;
                }
            }
            #pragma unroll
            for (int j = 0; j < NJ; ++j) wrow[j] = W[v * NJ + j];
        } else {
            #pragma unroll
            for (int b = 0; b < NBAT; ++b) { vx[b] = 0.f; vy[b] = 0.f; vz[b] = 0.f; }
            #pragma unroll
            for (int j = 0; j < NJ; ++j) wrow[j] = 0.f;
        }

        // skinning: vert = sum_j w_j * (A_j[:3,:3] vp + A_j[:3,3])
        #pragma unroll
        for (int b = 0; b < NBAT; ++b) {
            const float* Ab = Aws + (size_t)(bbase + b) * 192;          // uniform -> s_load
            float ax = 0.f, ay = 0.f, az = 0.f;
            #pragma unroll
            for (int j = 0; j < NJ; ++j) {
                const float* Aj = Ab + j * 12;
                float wj = wrow[j];
                float s0 = Aj[3];  s0 += Aj[0] * vx[b]; s0 += Aj[1]  * vy[b]; s0 += Aj[2]  * vz[b];
                float s1 = Aj[7];  s1 += Aj[4] * vx[b]; s1 += Aj[5]  * vy[b]; s1 += Aj[6]  * vz[b];
                float s2 = Aj[11]; s2 += Aj[8] * vx[b]; s2 += Aj[9]  * vy[b]; s2 += Aj[10] * vz[b];
                ax += wj * s0; ay += wj * s1; az += wj * s2;
            }
            vx[b] = ax; vy[b] = ay; vz[b] = az;
        }

        // finger vertices -> direct output (float32)
        if (valid) {
            int f = (v == 734) ? 0 : (v == 333) ? 1 : (v == 443) ? 2 : (v == 555) ? 3 : (v == 678) ? 4 : -1;
            if (f >= 0) {
                #pragma unroll
                for (int b = 0; b < NBAT; ++b) {
                    size_t o = (size_t)(bbase + b) * 63 + (size_t)(16 + f) * 3;
                    out[o + 0] = vx[b];
                    out[o + 1] = vy[b];
                    out[o + 2] = vz[b];
                }
            }
        }

        // stage vert tile for joint reduction
        #pragma unroll
        for (int b = 0; b < NBAT; ++b) {
            vertLDS[tid * 50 + b * 3 + 0] = vx[b];
            vertLDS[tid * 50 + b * 3 + 1] = vy[b];
            vertLDS[tid * 50 + b * 3 + 2] = vz[b];
        }
        __syncthreads();

        // joints[rb][rj] += sum_v Jr[v][rj] * vert[rb][v]
        const int vbase = tile * 256;
        const int lim = (NV - vbase < 256) ? (NV - vbase) : 256;
        #pragma unroll 8
        for (int vv = 0; vv < lim; ++vv) {
            float jr = Jr[(size_t)(vbase + vv) * NJ + rj];
            jacc0 += jr * vertLDS[vv * 50 + rb * 3 + 0];
            jacc1 += jr * vertLDS[vv * 50 + rb * 3 + 1];
            jacc2 += jr * vertLDS[vv * 50 + rb * 3 + 2];
        }
        __syncthreads();
    }

    size_t o = (size_t)(bbase + rb) * 63 + (size_t)rj * 3;
    out[o + 0] = jacc0;
    out[o + 1] = jacc1;
    out[o + 2] = jacc2;
}

extern "C" void kernel_launch(void* const* d_in, const int* in_sizes, int n_in,
                              void* d_out, int out_size, void* d_ws, size_t ws_size,
                              hipStream_t stream) {
    const float* beta = (const float*)d_in[0];
    const float* theta = (const float*)d_in[1];
    const float* sd   = (const float*)d_in[2];
    const float* pd   = (const float*)d_in[3];
    const float* vt   = (const float*)d_in[4];
    const float* Jr   = (const float*)d_in[5];
    const float* W    = (const float*)d_in[6];
    const float* hm   = (const float*)d_in[7];
    const float* hc   = (const float*)d_in[8];
    float* out = (float*)d_out;

    const int B = in_sizes[0] / NBETA;   // 8192

    float* SJ   = (float*)d_ws;                 // 480
    float* Jt   = SJ + 480;                     // 48
    float* Aws  = Jt + 48;                      // B*192
    float* pfws = Aws + (size_t)B * 192;        // B*135

    k_prejoint<<<3, 256, 0, stream>>>(sd, vt, Jr, SJ, Jt);
    k_batch<<<B, 64, 0, stream>>>(beta, theta, hm, hc, SJ, Jt, Aws, pfws);
    k_vert<<<B / NBAT, 256, 0, stream>>>(beta, sd, pd, vt, Jr, W, Aws, pfws, out);
}

// Round 9
// 546.693 us; speedup vs baseline: 1.7847x; 1.7847x over previous
//
#include <hip/hip_runtime.h>
#include <hip/hip_bf16.h>

#define NV 778
#define NJ 16
#define NBETA 10
#define NP 135
#define NTHETA 15
#define SD_COLS 2334   // NV*3
#define NBAT 8         // batches per block in k_vert (16->8: VGPR<128, LDS 25.6KB, grid 1024)

__device__ __constant__ int c_par[16] = {-1,0,1,2,0,4,5,0,7,8,0,10,11,0,13,14};

// ---------------- Kernel 1: SJ[k][j][c] (10x16x3) and Jt[j][c] (16x3) ----------------
__global__ void k_prejoint(const float* __restrict__ sd, const float* __restrict__ vt,
                           const float* __restrict__ Jr,
                           float* __restrict__ SJ, float* __restrict__ Jt)
{
    int o = blockIdx.x * blockDim.x + threadIdx.x;
    if (o < 480) {
        int k = o / 48, rem = o % 48, j = rem / 3, c = rem % 3;
        float acc = 0.f;
        for (int v = 0; v < NV; ++v) acc += sd[k * SD_COLS + v * 3 + c] * Jr[v * NJ + j];
        SJ[o] = acc;
    } else if (o < 528) {
        int idx = o - 480, j = idx / 3, c = idx % 3;
        float acc = 0.f;
        for (int v = 0; v < NV; ++v) acc += vt[v * 3 + c] * Jr[v * NJ + j];
        Jt[idx] = acc;
    }
}

// ---------------- Kernel 2: per-batch pose -> Rs -> chain -> A, pose_feature --------
// pfws written TRANSPOSED: pf_t[p * Btot + b] so k_vert gets contiguous batches.
__global__ __launch_bounds__(64) void k_batch(
    const float* __restrict__ beta, const float* __restrict__ theta,
    const float* __restrict__ hm, const float* __restrict__ hc,
    const float* __restrict__ SJ, const float* __restrict__ Jt,
    float* __restrict__ Aws, float* __restrict__ pfws, int Btot)
{
    const int b = blockIdx.x;
    const int t = threadIdx.x;
    __shared__ float th48[48];
    __shared__ float Rsh[16][9];
    __shared__ float JL[16][3];

    // step 1: full pose = g_rot ++ (pose12 @ hc[:12] + hm)
    if (t < 45) {
        float acc = hm[t];
        #pragma unroll
        for (int k = 0; k < 12; ++k) acc += theta[b * NTHETA + 3 + k] * hc[k * 45 + t];
        th48[3 + t] = acc;
    }
    if (t >= 45 && t < 48) th48[t - 45] = theta[b * NTHETA + (t - 45)];
    __syncthreads();

    // step 2: t<16 Rodrigues; t in [16,64) -> J = Jt + beta @ SJ
    if (t < 16) {
        float tx = th48[3 * t], ty = th48[3 * t + 1], tz = th48[3 * t + 2];
        float px = tx + 1e-8f, py = ty + 1e-8f, pz = tz + 1e-8f;
        float ang = sqrtf(px * px + py * py + pz * pz);
        float nx = tx / ang, ny = ty / ang, nz = tz / ang;
        float half = 0.5f * ang;
        float w = cosf(half), s = sinf(half);
        float qx = s * nx, qy = s * ny, qz = s * nz;
        float qn = sqrtf(w * w + qx * qx + qy * qy + qz * qz);
        w /= qn; qx /= qn; qy /= qn; qz /= qn;
        float w2 = w * w, x2 = qx * qx, y2 = qy * qy, z2 = qz * qz;
        float wx = w * qx, wy = w * qy, wz = w * qz;
        float xy = qx * qy, xz = qx * qz, yz = qy * qz;
        float* R = Rsh[t];
        R[0] = w2 + x2 - y2 - z2; R[1] = 2.f * xy - 2.f * wz; R[2] = 2.f * wy + 2.f * xz;
        R[3] = 2.f * wz + 2.f * xy; R[4] = w2 - x2 + y2 - z2; R[5] = 2.f * yz - 2.f * wx;
        R[6] = 2.f * xz - 2.f * wy; R[7] = 2.f * wx + 2.f * yz; R[8] = w2 - x2 - y2 + z2;
    } else {
        int idx = t - 16;           // 0..47
        int j = idx / 3, c = idx % 3;
        float acc = Jt[idx];
        #pragma unroll
        for (int k = 0; k < NBETA; ++k) acc += beta[b * NBETA + k] * SJ[k * 48 + idx];
        JL[j][c] = acc;
    }
    __syncthreads();

    // step 3: t<16 kinematic chain -> A; others pose_feature (transposed write)
    if (t < 16) {
        int path[4]; int d = 0; int i = t;
        while (i >= 0) { path[d++] = i; i = c_par[i]; }
        float GR[9], Gt3[3];
        #pragma unroll
        for (int e = 0; e < 9; ++e) GR[e] = Rsh[0][e];
        Gt3[0] = JL[0][0]; Gt3[1] = JL[0][1]; Gt3[2] = JL[0][2];
        for (int s2 = d - 2; s2 >= 0; --s2) {
            int i2 = path[s2];
            int pa = c_par[i2];
            float ti0 = JL[i2][0] - JL[pa][0];
            float ti1 = JL[i2][1] - JL[pa][1];
            float ti2 = JL[i2][2] - JL[pa][2];
            float NR[9], Nt[3];
            #pragma unroll
            for (int r = 0; r < 3; ++r) {
                #pragma unroll
                for (int c = 0; c < 3; ++c) {
                    NR[r * 3 + c] = GR[r * 3 + 0] * Rsh[i2][0 * 3 + c]
                                  + GR[r * 3 + 1] * Rsh[i2][1 * 3 + c]
                                  + GR[r * 3 + 2] * Rsh[i2][2 * 3 + c];
                }
                Nt[r] = GR[r * 3 + 0] * ti0 + GR[r * 3 + 1] * ti1 + GR[r * 3 + 2] * ti2 + Gt3[r];
            }
            #pragma unroll
            for (int e = 0; e < 9; ++e) GR[e] = NR[e];
            Gt3[0] = Nt[0]; Gt3[1] = Nt[1]; Gt3[2] = Nt[2];
        }
        float jx = JL[t][0], jy = JL[t][1], jz = JL[t][2];
        float* A = Aws + (size_t)b * 192 + t * 12;
        #pragma unroll
        for (int r = 0; r < 3; ++r) {
            A[r * 4 + 0] = GR[r * 3 + 0];
            A[r * 4 + 1] = GR[r * 3 + 1];
            A[r * 4 + 2] = GR[r * 3 + 2];
            A[r * 4 + 3] = Gt3[r] - (GR[r * 3 + 0] * jx + GR[r * 3 + 1] * jy + GR[r * 3 + 2] * jz);
        }
    } else {
        int idx = t - 16;           // 0..47
        #pragma unroll
        for (int it = 0; it < 3; ++it) {
            int p = idx + it * 48;
            if (p < NP) {
                int j = 1 + p / 9, e = p % 9;
                float dlt = (e == 0 || e == 4 || e == 8) ? 1.f : 0.f;
                pfws[(size_t)p * Btot + b] = Rsh[j][e] - dlt;   // transposed [p][b]
            }
        }
    }
}

// ---------------- Kernel 3: vertices + skinning + joint regression ------------------
// 256 thr, NBAT=8 batches/block, grid B/8=1024. Reduction: (rb=tid&7, rj=(tid>>3)&15,
// half=tid>>7) — each (rb,rj) covered by 2 threads over half the vertex tile each.
__global__ __launch_bounds__(256, 4) void k_vert(
    const float* __restrict__ beta, const float* __restrict__ sd, const float* __restrict__ pd,
    const float* __restrict__ vt, const float* __restrict__ Jr, const float* __restrict__ W,
    const float* __restrict__ Aws, const float* __restrict__ pfws, int Btot,
    float* __restrict__ out)
{
    __shared__ float vertLDS[256 * 25];   // stride 25: coprime with 32 banks -> 2-way max (free)
    const int tid = threadIdx.x;
    const int bbase = blockIdx.x * NBAT;
    const int rb = tid & 7;
    const int rj = (tid >> 3) & 15;
    const int half = tid >> 7;
    float jacc0 = 0.f, jacc1 = 0.f, jacc2 = 0.f;

    for (int tile = 0; tile < 4; ++tile) {
        const int v = tile * 256 + tid;
        const bool valid = v < NV;
        float vx[NBAT], vy[NBAT], vz[NBAT];
        float wrow[NJ];

        if (valid) {
            float sdc0[NBETA], sdc1[NBETA], sdc2[NBETA];
            #pragma unroll
            for (int k = 0; k < NBETA; ++k) {
                sdc0[k] = sd[k * SD_COLS + v * 3 + 0];
                sdc1[k] = sd[k * SD_COLS + v * 3 + 1];
                sdc2[k] = sd[k * SD_COLS + v * 3 + 2];
            }
            float vt0 = vt[v * 3 + 0], vt1 = vt[v * 3 + 1], vt2 = vt[v * 3 + 2];
            #pragma unroll
            for (int b = 0; b < NBAT; ++b) {
                float ax = vt0, ay = vt1, az = vt2;
                #pragma unroll
                for (int k = 0; k < NBETA; ++k) {
                    float be = beta[(size_t)(bbase + b) * NBETA + k];   // uniform -> s_load
                    ax += be * sdc0[k]; ay += be * sdc1[k]; az += be * sdc2[k];
                }
                vx[b] = ax; vy[b] = ay; vz[b] = az;
            }
            // pose-blend: pf transposed [p][b] -> one s_load_dwordx8 per p
            for (int p = 0; p < NP; ++p) {
                float p0 = pd[p * SD_COLS + v * 3 + 0];
                float p1 = pd[p * SD_COLS + v * 3 + 1];
                float p2 = pd[p * SD_COLS + v * 3 + 2];
                #pragma unroll
                for (int b = 0; b < NBAT; ++b) {
                    float f = pfws[(size_t)p * Btot + bbase + b];       // contiguous uniform
                    vx[b] += f * p0; vy[b] += f * p1; vz[b] += f * p2;
                }
            }
            #pragma unroll
            for (int j = 0; j < NJ; ++j) wrow[j] = W[v * NJ + j];
        } else {
            #pragma unroll
            for (int b = 0; b < NBAT; ++b) { vx[b] = 0.f; vy[b] = 0.f; vz[b] = 0.f; }
            #pragma unroll
            for (int j = 0; j < NJ; ++j) wrow[j] = 0.f;
        }

        // skinning: vert = sum_j w_j * (A_j[:3,:3] vp + A_j[:3,3])
        #pragma unroll
        for (int b = 0; b < NBAT; ++b) {
            const float* Ab = Aws + (size_t)(bbase + b) * 192;          // uniform -> s_load
            float ax = 0.f, ay = 0.f, az = 0.f;
            #pragma unroll
            for (int j = 0; j < NJ; ++j) {
                const float* Aj = Ab + j * 12;
                float wj = wrow[j];
                float s0 = Aj[3];  s0 += Aj[0] * vx[b]; s0 += Aj[1]  * vy[b]; s0 += Aj[2]  * vz[b];
                float s1 = Aj[7];  s1 += Aj[4] * vx[b]; s1 += Aj[5]  * vy[b]; s1 += Aj[6]  * vz[b];
                float s2 = Aj[11]; s2 += Aj[8] * vx[b]; s2 += Aj[9]  * vy[b]; s2 += Aj[10] * vz[b];
                ax += wj * s0; ay += wj * s1; az += wj * s2;
            }
            vx[b] = ax; vy[b] = ay; vz[b] = az;
        }

        // finger vertices -> direct output (float32)
        if (valid) {
            int f = (v == 734) ? 0 : (v == 333) ? 1 : (v == 443) ? 2 : (v == 555) ? 3 : (v == 678) ? 4 : -1;
            if (f >= 0) {
                #pragma unroll
                for (int b = 0; b < NBAT; ++b) {
                    size_t o = (size_t)(bbase + b) * 63 + (size_t)(16 + f) * 3;
                    out[o + 0] = vx[b];
                    out[o + 1] = vy[b];
                    out[o + 2] = vz[b];
                }
            }
        }

        // stage vert tile for joint reduction
        #pragma unroll
        for (int b = 0; b < NBAT; ++b) {
            vertLDS[tid * 25 + b * 3 + 0] = vx[b];
            vertLDS[tid * 25 + b * 3 + 1] = vy[b];
            vertLDS[tid * 25 + b * 3 + 2] = vz[b];
        }
        __syncthreads();

        // joints[rb][rj] += sum_v Jr[v][rj] * vert[rb][v]  (each half does 128 vv)
        const int vbase = tile * 256;
        int lim = NV - vbase; if (lim > 256) lim = 256;
        int lo = half * 128;
        int hi = lo + 128; if (hi > lim) hi = lim;
        for (int vv = lo; vv < hi; ++vv) {
            float jr = Jr[(size_t)(vbase + vv) * NJ + rj];
            jacc0 += jr * vertLDS[vv * 25 + rb * 3 + 0];
            jacc1 += jr * vertLDS[vv * 25 + rb * 3 + 1];
            jacc2 += jr * vertLDS[vv * 25 + rb * 3 + 2];
        }
        __syncthreads();
    }

    // combine the two halves' partials via LDS (reuse vertLDS)
    vertLDS[tid * 3 + 0] = jacc0;
    vertLDS[tid * 3 + 1] = jacc1;
    vertLDS[tid * 3 + 2] = jacc2;
    __syncthreads();
    if (tid < 128) {
        float j0 = vertLDS[tid * 3 + 0] + vertLDS[(tid + 128) * 3 + 0];
        float j1 = vertLDS[tid * 3 + 1] + vertLDS[(tid + 128) * 3 + 1];
        float j2 = vertLDS[tid * 3 + 2] + vertLDS[(tid + 128) * 3 + 2];
        size_t o = (size_t)(bbase + rb) * 63 + (size_t)rj * 3;
        out[o + 0] = j0;
        out[o + 1] = j1;
        out[o + 2] = j2;
    }
}

extern "C" void kernel_launch(void* const* d_in, const int* in_sizes, int n_in,
                              void* d_out, int out_size, void* d_ws, size_t ws_size,
                              hipStream_t stream) {
    const float* beta = (const float*)d_in[0];
    const float* theta = (const float*)d_in[1];
    const float* sd   = (const float*)d_in[2];
    const float* pd   = (const float*)d_in[3];
    const float* vt   = (const float*)d_in[4];
    const float* Jr   = (const float*)d_in[5];
    const float* W    = (const float*)d_in[6];
    const float* hm   = (const float*)d_in[7];
    const float* hc   = (const float*)d_in[8];
    float* out = (float*)d_out;

    const int B = in_sizes[0] / NBETA;   // 8192

    float* SJ   = (float*)d_ws;                 // 480
    float* Jt   = SJ + 480;                     // 48
    float* Aws  = Jt + 48;                      // B*192
    float* pfws = Aws + (size_t)B * 192;        // NP*B (transposed [p][b])

    k_prejoint<<<3, 256, 0, stream>>>(sd, vt, Jr, SJ, Jt);
    k_batch<<<B, 64, 0, stream>>>(beta, theta, hm, hc, SJ, Jt, Aws, pfws, B);
    k_vert<<<B / NBAT, 256, 0, stream>>>(beta, sd, pd, vt, Jr, W, Aws, pfws, B, out);
}

// Round 10
// 356.708 us; speedup vs baseline: 2.7352x; 1.5326x over previous
//
#include <hip/hip_runtime.h>
#include <hip/hip_bf16.h>

#define NV 778
#define NJ 16
#define NBETA 10
#define NP 135
#define NTHETA 15
#define SD_COLS 2334   // NV*3
#define NBAT 8         // batches per block in k_vert

__device__ __constant__ int c_par[16] = {-1,0,1,2,0,4,5,0,7,8,0,10,11,0,13,14};

// ---------------- Kernel 1: SJ[k][j][c] (10x16x3) and Jt[j][c] (16x3) ----------------
// 528 blocks x 64 threads, wave-shuffle reduce over vertices.
__global__ __launch_bounds__(64) void k_prejoint(
    const float* __restrict__ sd, const float* __restrict__ vt,
    const float* __restrict__ Jr, float* __restrict__ SJ, float* __restrict__ Jt)
{
    const int o = blockIdx.x;
    const int t = threadIdx.x;
    float acc = 0.f;
    if (o < 480) {
        int k = o / 48, rem = o % 48, j = rem / 3, c = rem % 3;
        for (int v = t; v < NV; v += 64) acc += sd[k * SD_COLS + v * 3 + c] * Jr[v * NJ + j];
    } else {
        int idx = o - 480, j = idx / 3, c = idx % 3;
        for (int v = t; v < NV; v += 64) acc += vt[v * 3 + c] * Jr[v * NJ + j];
    }
    #pragma unroll
    for (int off = 32; off > 0; off >>= 1) acc += __shfl_down(acc, off);
    if (t == 0) {
        if (o < 480) SJ[o] = acc;
        else Jt[o - 480] = acc;
    }
}

// ---------------- Kernel 2 (fused): pose prologue + vertices + skinning + joints ----
// Each block owns NBAT=8 batches end-to-end. Prologue computes th -> Rs -> chain -> A
// and pose_feature for its 8 batches entirely in LDS (no cross-kernel HBM round-trip,
// no cross-XCD coherence traffic). Main loop identical to round-9 k_vert but reads
// A/pf from LDS broadcast.
__global__ __launch_bounds__(256, 4) void k_fused(
    const float* __restrict__ beta, const float* __restrict__ theta,
    const float* __restrict__ sd, const float* __restrict__ pd,
    const float* __restrict__ vt, const float* __restrict__ Jr,
    const float* __restrict__ W, const float* __restrict__ hm,
    const float* __restrict__ hc, const float* __restrict__ SJ,
    const float* __restrict__ Jt, float* __restrict__ out)
{
    // LDS plan (36,096 B total -> 4 blocks/CU):
    //   [0, 25600)        vertLDS[256*25]  (main loop)   OVERLAYS prologue th/Rsh/JL
    //   [25600, 31744)    A_lds[8][16][12]
    //   [31744, 36096)    pf_lds[135][8]  (p-major, 8 batches contiguous -> ds_read_b128)
    __shared__ __align__(16) char smem[25600 + 6144 + 4352];
    float* const vertLDS = (float*)smem;
    float* const A_lds   = (float*)(smem + 25600);
    float* const pf_lds  = (float*)(smem + 25600 + 6144);
    // prologue overlay inside vertLDS region:
    float* const th  = (float*)smem;                   // [8][48]   1536 B
    float* const Rsh = (float*)(smem + 1536);          // [8][16][9] 4608 B
    float* const JLs = (float*)(smem + 1536 + 4608);   // [8][16][3] 1536 B

    const int tid = threadIdx.x;
    const int bbase = blockIdx.x * NBAT;

    // ---- prologue phase 1: full pose th[b][0..47] ----
    for (int o = tid; o < NBAT * 48; o += 256) {
        int b = o / 48, i = o % 48;
        float acc;
        if (i < 3) {
            acc = theta[(size_t)(bbase + b) * NTHETA + i];
        } else {
            acc = hm[i - 3];
            #pragma unroll
            for (int k = 0; k < 12; ++k)
                acc += theta[(size_t)(bbase + b) * NTHETA + 3 + k] * hc[k * 45 + (i - 3)];
        }
        th[b * 48 + i] = acc;
    }
    __syncthreads();

    // ---- phase 2: Rodrigues (R) + joint positions (JL) per (b, j) ----
    if (tid < NBAT * 16) {
        int b = tid >> 4, j = tid & 15;
        float tx = th[b * 48 + 3 * j], ty = th[b * 48 + 3 * j + 1], tz = th[b * 48 + 3 * j + 2];
        float px = tx + 1e-8f, py = ty + 1e-8f, pz = tz + 1e-8f;
        float ang = sqrtf(px * px + py * py + pz * pz);
        float nx = tx / ang, ny = ty / ang, nz = tz / ang;
        float half = 0.5f * ang;
        float w = cosf(half), s = sinf(half);
        float qx = s * nx, qy = s * ny, qz = s * nz;
        float qn = sqrtf(w * w + qx * qx + qy * qy + qz * qz);
        w /= qn; qx /= qn; qy /= qn; qz /= qn;
        float w2 = w * w, x2 = qx * qx, y2 = qy * qy, z2 = qz * qz;
        float wx = w * qx, wy = w * qy, wz = w * qz;
        float xy = qx * qy, xz = qx * qz, yz = qy * qz;
        float* R = Rsh + (b * 16 + j) * 9;
        R[0] = w2 + x2 - y2 - z2; R[1] = 2.f * xy - 2.f * wz; R[2] = 2.f * wy + 2.f * xz;
        R[3] = 2.f * wz + 2.f * xy; R[4] = w2 - x2 + y2 - z2; R[5] = 2.f * yz - 2.f * wx;
        R[6] = 2.f * xz - 2.f * wy; R[7] = 2.f * wx + 2.f * yz; R[8] = w2 - x2 - y2 + z2;
        #pragma unroll
        for (int c = 0; c < 3; ++c) {
            float acc = Jt[j * 3 + c];
            #pragma unroll
            for (int k = 0; k < NBETA; ++k)
                acc += beta[(size_t)(bbase + b) * NBETA + k] * SJ[k * 48 + j * 3 + c];
            JLs[(b * 16 + j) * 3 + c] = acc;
        }
    }
    __syncthreads();

    // ---- phase 3: kinematic chain -> A_lds; pose_feature -> pf_lds ----
    if (tid < NBAT * 16) {
        int b = tid >> 4, j = tid & 15;
        int path[4]; int d = 0; int i = j;
        while (i >= 0) { path[d++] = i; i = c_par[i]; }
        float GR[9], Gt3[3];
        #pragma unroll
        for (int e = 0; e < 9; ++e) GR[e] = Rsh[(b * 16 + 0) * 9 + e];
        Gt3[0] = JLs[(b * 16) * 3 + 0]; Gt3[1] = JLs[(b * 16) * 3 + 1]; Gt3[2] = JLs[(b * 16) * 3 + 2];
        for (int s2 = d - 2; s2 >= 0; --s2) {
            int i2 = path[s2];
            int pa = c_par[i2];
            float ti0 = JLs[(b * 16 + i2) * 3 + 0] - JLs[(b * 16 + pa) * 3 + 0];
            float ti1 = JLs[(b * 16 + i2) * 3 + 1] - JLs[(b * 16 + pa) * 3 + 1];
            float ti2 = JLs[(b * 16 + i2) * 3 + 2] - JLs[(b * 16 + pa) * 3 + 2];
            const float* Ri = Rsh + (b * 16 + i2) * 9;
            float NR[9], Nt[3];
            #pragma unroll
            for (int r = 0; r < 3; ++r) {
                #pragma unroll
                for (int c = 0; c < 3; ++c) {
                    NR[r * 3 + c] = GR[r * 3 + 0] * Ri[0 * 3 + c]
                                  + GR[r * 3 + 1] * Ri[1 * 3 + c]
                                  + GR[r * 3 + 2] * Ri[2 * 3 + c];
                }
                Nt[r] = GR[r * 3 + 0] * ti0 + GR[r * 3 + 1] * ti1 + GR[r * 3 + 2] * ti2 + Gt3[r];
            }
            #pragma unroll
            for (int e = 0; e < 9; ++e) GR[e] = NR[e];
            Gt3[0] = Nt[0]; Gt3[1] = Nt[1]; Gt3[2] = Nt[2];
        }
        float jx = JLs[(b * 16 + j) * 3 + 0], jy = JLs[(b * 16 + j) * 3 + 1], jz = JLs[(b * 16 + j) * 3 + 2];
        float* A = A_lds + (b * 16 + j) * 12;
        #pragma unroll
        for (int r = 0; r < 3; ++r) {
            A[r * 4 + 0] = GR[r * 3 + 0];
            A[r * 4 + 1] = GR[r * 3 + 1];
            A[r * 4 + 2] = GR[r * 3 + 2];
            A[r * 4 + 3] = Gt3[r] - (GR[r * 3 + 0] * jx + GR[r * 3 + 1] * jy + GR[r * 3 + 2] * jz);
        }
        if (j > 0) {
            #pragma unroll
            for (int e = 0; e < 9; ++e) {
                float dlt = (e == 0 || e == 4 || e == 8) ? 1.f : 0.f;
                pf_lds[((j - 1) * 9 + e) * NBAT + b] = Rsh[(b * 16 + j) * 9 + e] - dlt;
            }
        }
    }
    __syncthreads();   // prologue scratch (th/Rsh/JL) dead; vertLDS region free

    // ---- main loop: vertices + skinning + joint regression ----
    const int rb = tid & 7;
    const int rj = (tid >> 3) & 15;
    const int half = tid >> 7;
    float jacc0 = 0.f, jacc1 = 0.f, jacc2 = 0.f;

    for (int tile = 0; tile < 4; ++tile) {
        const int v = tile * 256 + tid;
        const bool valid = v < NV;
        float vx[NBAT], vy[NBAT], vz[NBAT];
        float wrow[NJ];

        if (valid) {
            float sdc0[NBETA], sdc1[NBETA], sdc2[NBETA];
            #pragma unroll
            for (int k = 0; k < NBETA; ++k) {
                sdc0[k] = sd[k * SD_COLS + v * 3 + 0];
                sdc1[k] = sd[k * SD_COLS + v * 3 + 1];
                sdc2[k] = sd[k * SD_COLS + v * 3 + 2];
            }
            float vt0 = vt[v * 3 + 0], vt1 = vt[v * 3 + 1], vt2 = vt[v * 3 + 2];
            #pragma unroll
            for (int b = 0; b < NBAT; ++b) {
                float ax = vt0, ay = vt1, az = vt2;
                #pragma unroll
                for (int k = 0; k < NBETA; ++k) {
                    float be = beta[(size_t)(bbase + b) * NBETA + k];   // uniform -> s_load
                    ax += be * sdc0[k]; ay += be * sdc1[k]; az += be * sdc2[k];
                }
                vx[b] = ax; vy[b] = ay; vz[b] = az;
            }
            // pose-blend: pf from LDS broadcast (contiguous 8 -> ds_read_b128 x2)
            for (int p = 0; p < NP; ++p) {
                float p0 = pd[p * SD_COLS + v * 3 + 0];
                float p1 = pd[p * SD_COLS + v * 3 + 1];
                float p2 = pd[p * SD_COLS + v * 3 + 2];
                #pragma unroll
                for (int b = 0; b < NBAT; ++b) {
                    float f = pf_lds[p * NBAT + b];
                    vx[b] += f * p0; vy[b] += f * p1; vz[b] += f * p2;
                }
            }
            #pragma unroll
            for (int j = 0; j < NJ; ++j) wrow[j] = W[v * NJ + j];
        } else {
            #pragma unroll
            for (int b = 0; b < NBAT; ++b) { vx[b] = 0.f; vy[b] = 0.f; vz[b] = 0.f; }
            #pragma unroll
            for (int j = 0; j < NJ; ++j) wrow[j] = 0.f;
        }

        // skinning from LDS-resident A
        #pragma unroll
        for (int b = 0; b < NBAT; ++b) {
            const float* Ab = A_lds + b * 192;
            float ax = 0.f, ay = 0.f, az = 0.f;
            #pragma unroll
            for (int j = 0; j < NJ; ++j) {
                const float* Aj = Ab + j * 12;
                float wj = wrow[j];
                float s0 = Aj[3];  s0 += Aj[0] * vx[b]; s0 += Aj[1]  * vy[b]; s0 += Aj[2]  * vz[b];
                float s1 = Aj[7];  s1 += Aj[4] * vx[b]; s1 += Aj[5]  * vy[b]; s1 += Aj[6]  * vz[b];
                float s2 = Aj[11]; s2 += Aj[8] * vx[b]; s2 += Aj[9]  * vy[b]; s2 += Aj[10] * vz[b];
                ax += wj * s0; ay += wj * s1; az += wj * s2;
            }
            vx[b] = ax; vy[b] = ay; vz[b] = az;
        }

        // finger vertices -> direct output (float32)
        if (valid) {
            int f = (v == 734) ? 0 : (v == 333) ? 1 : (v == 443) ? 2 : (v == 555) ? 3 : (v == 678) ? 4 : -1;
            if (f >= 0) {
                #pragma unroll
                for (int b = 0; b < NBAT; ++b) {
                    size_t o = (size_t)(bbase + b) * 63 + (size_t)(16 + f) * 3;
                    out[o + 0] = vx[b];
                    out[o + 1] = vy[b];
                    out[o + 2] = vz[b];
                }
            }
        }

        // stage vert tile for joint reduction (stride 25: conflict-free)
        #pragma unroll
        for (int b = 0; b < NBAT; ++b) {
            vertLDS[tid * 25 + b * 3 + 0] = vx[b];
            vertLDS[tid * 25 + b * 3 + 1] = vy[b];
            vertLDS[tid * 25 + b * 3 + 2] = vz[b];
        }
        __syncthreads();

        // joints[rb][rj] += sum_v Jr[v][rj] * vert[rb][v]  (each half does 128 vv)
        const int vbase = tile * 256;
        int lim = NV - vbase; if (lim > 256) lim = 256;
        int lo = half * 128;
        int hi = lo + 128; if (hi > lim) hi = lim;
        for (int vv = lo; vv < hi; ++vv) {
            float jr = Jr[(size_t)(vbase + vv) * NJ + rj];
            jacc0 += jr * vertLDS[vv * 25 + rb * 3 + 0];
            jacc1 += jr * vertLDS[vv * 25 + rb * 3 + 1];
            jacc2 += jr * vertLDS[vv * 25 + rb * 3 + 2];
        }
        __syncthreads();
    }

    // combine the two halves' partials via LDS (reuse vertLDS)
    vertLDS[tid * 3 + 0] = jacc0;
    vertLDS[tid * 3 + 1] = jacc1;
    vertLDS[tid * 3 + 2] = jacc2;
    __syncthreads();
    if (tid < 128) {
        float j0 = vertLDS[tid * 3 + 0] + vertLDS[(tid + 128) * 3 + 0];
        float j1 = vertLDS[tid * 3 + 1] + vertLDS[(tid + 128) * 3 + 1];
        float j2 = vertLDS[tid * 3 + 2] + vertLDS[(tid + 128) * 3 + 2];
        size_t o = (size_t)(bbase + rb) * 63 + (size_t)rj * 3;
        out[o + 0] = j0;
        out[o + 1] = j1;
        out[o + 2] = j2;
    }
}

extern "C" void kernel_launch(void* const* d_in, const int* in_sizes, int n_in,
                              void* d_out, int out_size, void* d_ws, size_t ws_size,
                              hipStream_t stream) {
    const float* beta = (const float*)d_in[0];
    const float* theta = (const float*)d_in[1];
    const float* sd   = (const float*)d_in[2];
    const float* pd   = (const float*)d_in[3];
    const float* vt   = (const float*)d_in[4];
    const float* Jr   = (const float*)d_in[5];
    const float* W    = (const float*)d_in[6];
    const float* hm   = (const float*)d_in[7];
    const float* hc   = (const float*)d_in[8];
    float* out = (float*)d_out;

    const int B = in_sizes[0] / NBETA;   // 8192

    float* SJ = (float*)d_ws;            // 480
    float* Jt = SJ + 480;                // 48

    k_prejoint<<<528, 64, 0, stream>>>(sd, vt, Jr, SJ, Jt);
    k_fused<<<B / NBAT, 256, 0, stream>>>(beta, theta, sd, pd, vt, Jr, W, hm, hc, SJ, Jt, out);
}